// Round 1
// baseline (95.293 us; speedup 1.0000x reference)
//
#include <hip/hip_runtime.h>
#include <stdint.h>
#include <math.h>

#define T_CTX 32
#define C_EMB 128
#define H_DIM 64
#define NB    8      // batches per wave
#define WROW  136    // padded LDS row stride (bf16 elems) for W^T

typedef __bf16 bf16x8 __attribute__((ext_vector_type(8)));
typedef float  f32x16 __attribute__((ext_vector_type(16)));

union Frag {
  uint32_t w[4];
  bf16x8   v;
};
static_assert(sizeof(Frag) == 16, "frag size");

__device__ __forceinline__ uint32_t cvt_pk(float a, float b) {
  uint32_t r;
  asm("v_cvt_pk_bf16_f32 %0, %1, %2" : "=v"(r) : "v"(a), "v"(b));
  return r;
}
__device__ __forceinline__ void swap32(uint32_t &a, uint32_t &b) {
  asm("v_permlane32_swap_b32 %0, %1" : "+v"(a), "+v"(b));
}
__device__ __forceinline__ float bf_lo_f(uint32_t w) {  // low bf16 -> float
  union { uint32_t u; float f; } c; c.u = w << 16; return c.f;
}
__device__ __forceinline__ float bf_hi_f(uint32_t w) {  // high bf16 -> float
  union { uint32_t u; float f; } c; c.u = w & 0xffff0000u; return c.f;
}

__device__ __forceinline__ f32x16 mfma(const Frag &a, const Frag &b, const f32x16 &c) {
  return __builtin_amdgcn_mfma_f32_32x32x16_bf16(a.v, b.v, c, 0, 0, 0);
}

// Build hi/lo bf16 fragments from 8 consecutive floats.
__device__ __forceinline__ void cvt8(const float4 &a, const float4 &b, Frag &h, Frag &l) {
  float f[8] = {a.x, a.y, a.z, a.w, b.x, b.y, b.z, b.w};
#pragma unroll
  for (int j = 0; j < 4; ++j) {
    uint32_t hw = cvt_pk(f[2 * j], f[2 * j + 1]);
    float r0 = f[2 * j]     - bf_lo_f(hw);
    float r1 = f[2 * j + 1] - bf_hi_f(hw);
    h.w[j] = hw;
    l.w[j] = cvt_pk(r0, r1);
  }
}

// From 16 accumulator values (rows crow(r,hi) = (r&3)+8*(r>>2)+4*hi, col = lane&31)
// build two A/B fragments: f0 covers rows 0..15, f1 rows 16..31, with
// lane(lo) holding 8 consecutive rows [8*(lane>>5) .. +7] of its column.
__device__ __forceinline__ void make2(const float *a, Frag &f0, Frag &f1) {
  uint32_t x, y;
  x = cvt_pk(a[0], a[1]);   y = cvt_pk(a[4], a[5]);   swap32(x, y); f0.w[0] = x; f0.w[2] = y;
  x = cvt_pk(a[2], a[3]);   y = cvt_pk(a[6], a[7]);   swap32(x, y); f0.w[1] = x; f0.w[3] = y;
  x = cvt_pk(a[8], a[9]);   y = cvt_pk(a[12], a[13]); swap32(x, y); f1.w[0] = x; f1.w[2] = y;
  x = cvt_pk(a[10], a[11]); y = cvt_pk(a[14], a[15]); swap32(x, y); f1.w[1] = x; f1.w[3] = y;
}

__global__ __launch_bounds__(256) void head_fused(
    const float* __restrict__ x, const float* __restrict__ Wk,
    const float* __restrict__ Wq, const float* __restrict__ Wv,
    float* __restrict__ out, int nbatch) {
  __shared__ unsigned short wt[3 * H_DIM * WROW];  // W^T bf16: slot0=Wq,1=Wk,2=Wv

  const int tid = threadIdx.x;
  // ---- stage W^T into LDS (once per block) ----
  {
    const float* Ws[3] = {Wq, Wk, Wv};
#pragma unroll
    for (int wi = 0; wi < 3; ++wi) {
      const float* W = Ws[wi];
#pragma unroll
      for (int it = 0; it < 8; ++it) {
        int e = (it * 256 + tid) * 4;        // linear over [C][H], 4 consecutive h
        float4 f = *(const float4*)(W + e);
        int c = e >> 6, h = e & 63;
        uint32_t w01 = cvt_pk(f.x, f.y);
        uint32_t w23 = cvt_pk(f.z, f.w);
        unsigned short* bp = &wt[(wi * H_DIM + h) * WROW + c];
        bp[0 * WROW] = (unsigned short)(w01 & 0xffffu);
        bp[1 * WROW] = (unsigned short)(w01 >> 16);
        bp[2 * WROW] = (unsigned short)(w23 & 0xffffu);
        bp[3 * WROW] = (unsigned short)(w23 >> 16);
      }
    }
  }
  __syncthreads();

  const int wave = tid >> 6, lane = tid & 63;
  const int col = lane & 31, hi = lane >> 5;

  // per-lane W^T fragment base pointers (row = 32*tile + col, col-base = 8*hi)
  const unsigned short* wq0 = &wt[(0 * H_DIM + col) * WROW + hi * 8];
  const unsigned short* wq1 = wq0 + 32 * WROW;
  const unsigned short* wk0 = wq0 + 64 * WROW;
  const unsigned short* wk1 = wq0 + 96 * WROW;
  const unsigned short* wv0 = wq0 + 128 * WROW;
  const unsigned short* wv1 = wq0 + 160 * WROW;

  for (int it = 0; it < NB; ++it) {
    int batch = blockIdx.x * (4 * NB) + it * 4 + wave;
    if (batch >= nbatch) break;
    const float* xp = x + (size_t)batch * (T_CTX * C_EMB) + col * C_EMB + hi * 8;

    // ---- load X fragments (hi/lo split) ----
    Frag xh[8], xl[8];
#pragma unroll
    for (int kk = 0; kk < 8; ++kk) {
      float4 a = *(const float4*)(xp + kk * 16);
      float4 b = *(const float4*)(xp + kk * 16 + 4);
      cvt8(a, b, xh[kk], xl[kk]);
    }

    // ---- Qt = Wq^T · X^T  (lane col = t, acc rows = h) ----
    f32x16 q0{}, q1{};
#pragma unroll
    for (int kk = 0; kk < 8; ++kk) {
      Frag w0, w1;
      w0.v = *(const bf16x8*)(wq0 + kk * 16);
      w1.v = *(const bf16x8*)(wq1 + kk * 16);
      q0 = mfma(w0, xh[kk], q0); q0 = mfma(w0, xl[kk], q0);
      q1 = mfma(w1, xh[kk], q1); q1 = mfma(w1, xl[kk], q1);
    }
    Frag qf[4];
    { float t[16];
#pragma unroll
      for (int r = 0; r < 16; ++r) t[r] = q0[r];
      make2(t, qf[0], qf[1]);
#pragma unroll
      for (int r = 0; r < 16; ++r) t[r] = q1[r];
      make2(t, qf[2], qf[3]);
    }

    // ---- Kt = Wk^T · X^T ----
    f32x16 k0{}, k1{};
#pragma unroll
    for (int kk = 0; kk < 8; ++kk) {
      Frag w0, w1;
      w0.v = *(const bf16x8*)(wk0 + kk * 16);
      w1.v = *(const bf16x8*)(wk1 + kk * 16);
      k0 = mfma(w0, xh[kk], k0); k0 = mfma(w0, xl[kk], k0);
      k1 = mfma(w1, xh[kk], k1); k1 = mfma(w1, xl[kk], k1);
    }
    Frag kf[4];
    { float t[16];
#pragma unroll
      for (int r = 0; r < 16; ++r) t[r] = k0[r];
      make2(t, kf[0], kf[1]);
#pragma unroll
      for (int r = 0; r < 16; ++r) t[r] = k1[r];
      make2(t, kf[2], kf[3]);
    }

    // ---- V = X · Wv  (lane col = h, acc rows = t) ----
    f32x16 va{}, vb{};
#pragma unroll
    for (int kk = 0; kk < 8; ++kk) {
      Frag w0, w1;
      w0.v = *(const bf16x8*)(wv0 + kk * 16);
      w1.v = *(const bf16x8*)(wv1 + kk * 16);
      va = mfma(xh[kk], w0, va); va = mfma(xl[kk], w0, va);
      vb = mfma(xh[kk], w1, vb); vb = mfma(xl[kk], w1, vb);
    }

    // ---- S^T = K · Q^T  (lane col = q, acc rows = key) ----
    f32x16 st{};
#pragma unroll
    for (int ks = 0; ks < 4; ++ks) st = mfma(kf[ks], qf[ks], st);

    // ---- causal softmax over keys (fp32, in-lane 16 + partner via shfl) ----
    float p[16];
    float m = -INFINITY;
#pragma unroll
    for (int r = 0; r < 16; ++r) {
      int key = (r & 3) + 8 * (r >> 2) + 4 * hi;
      float sv = st[r] * 0.125f;
      p[r] = (key > col) ? -INFINITY : sv;
      m = fmaxf(m, p[r]);
    }
    m = fmaxf(m, __shfl_xor(m, 32));
    float sum = 0.f;
#pragma unroll
    for (int r = 0; r < 16; ++r) {
      p[r] = exp2f((p[r] - m) * 1.4426950408889634f);
      sum += p[r];
    }
    sum += __shfl_xor(sum, 32);
    float inv = 1.0f / sum;
#pragma unroll
    for (int r = 0; r < 16; ++r) p[r] *= inv;

    Frag pa0, pa1;
    make2(p, pa0, pa1);

    Frag vfa0, vfa1, vfb0, vfb1;
    { float t[16];
#pragma unroll
      for (int r = 0; r < 16; ++r) t[r] = va[r];
      make2(t, vfa0, vfa1);
#pragma unroll
      for (int r = 0; r < 16; ++r) t[r] = vb[r];
      make2(t, vfb0, vfb1);
    }

    // ---- O = P · V  (acc rows = t, lane col = h) ----
    f32x16 o0{}, o1{};
    o0 = mfma(pa0, vfa0, o0); o0 = mfma(pa1, vfa1, o0);
    o1 = mfma(pa0, vfb0, o1); o1 = mfma(pa1, vfb1, o1);

    // ---- store ----
    float* op = out + (size_t)batch * (T_CTX * H_DIM) + col;
#pragma unroll
    for (int r = 0; r < 16; ++r) {
      int trow = (r & 3) + 8 * (r >> 2) + 4 * hi;
      op[trow * H_DIM]      = o0[r];
      op[trow * H_DIM + 32] = o1[r];
    }
  }
}

extern "C" void kernel_launch(void* const* d_in, const int* in_sizes, int n_in,
                              void* d_out, int out_size, void* d_ws, size_t ws_size,
                              hipStream_t stream) {
  (void)n_in; (void)out_size; (void)d_ws; (void)ws_size;
  const float* x  = (const float*)d_in[0];
  const float* Wk = (const float*)d_in[1];
  const float* Wq = (const float*)d_in[2];
  const float* Wv = (const float*)d_in[3];
  float* out = (float*)d_out;
  int B = in_sizes[0] / (T_CTX * C_EMB);
  int grid = (B + 4 * NB - 1) / (4 * NB);
  head_fused<<<dim3(grid), dim3(256), 0, stream>>>(x, Wk, Wq, Wv, out, B);
}